// Round 12
// baseline (353.099 us; speedup 1.0000x reference)
//
#include <hip/hip_runtime.h>
#include <hip/hip_bf16.h>

// Problem constants
#define BB 8
#define TT 16
#define NNODE 10000
#define FF 64
#define HH 64
#define EE 1000000
#define MM 80000      // BB * NNODE
#define NCLS 3

#define NCHUNK 80     // src chunks per timestep (10 chunks per graph)
#define NPC 1000      // nodes per chunk
#define NSEG_H 16     // histogram edge segments
#define HW 20000      // histogram words (u8-packed: 4 bins/word = 80000 bins)
#define NSEG_B 32     // k_part blocks per timestep (x4 waves = 128 wave-segments/t)
#define NW 128        // wave-segments per timestep
#define EPW 7816      // edges per wave-segment (mult of 4; 128*7816 >= 1e6)
#define WCAP 48       // wave-private staging capacity per chunk
#define FLUSH_THR 24  // flush when staged count >= this
#define RCAP 152      // records per region (mean 97.7, sigma 9.9 -> 5.5 sigma headroom)
// Regions are fully dense: k_part sentinel-pads [gct,RCAP). Sentinel record:
// so in [1008,1023] (trash rows), d=0. a[] has 1024 rows; rows >=1000 never read.
#define AROWS 1024

// ---------------------------------------------------------------------------
// Kernel 1: per-timestep dst histogram, LDS-privatized, u8-packed, uint4 loads.
// ---------------------------------------------------------------------------
__global__ __launch_bounds__(256) void k_hist(const int* __restrict__ ei,
                                              unsigned int* __restrict__ part, int t0) {
    __shared__ unsigned int h[HW];   // 80 KB
    int seg = blockIdx.x, tloc = blockIdx.y, tg = t0 + tloc;
    for (int i = threadIdx.x; i < HW; i += 256) h[i] = 0u;
    __syncthreads();
    const uint4* dstp = (const uint4*)(ei + (size_t)tg * 2 * EE + EE
                                       + (size_t)seg * (EE / NSEG_H));
    for (int i = threadIdx.x; i < (EE / NSEG_H) / 4; i += 256) {
        uint4 d4 = dstp[i];
        atomicAdd(&h[d4.x >> 2], 1u << ((d4.x & 3u) * 8u));
        atomicAdd(&h[d4.y >> 2], 1u << ((d4.y & 3u) * 8u));
        atomicAdd(&h[d4.z >> 2], 1u << ((d4.z & 3u) * 8u));
        atomicAdd(&h[d4.w >> 2], 1u << ((d4.w & 3u) * 8u));
    }
    __syncthreads();
    unsigned int* outp = part + ((size_t)tloc * NSEG_H + seg) * HW;
    for (int i = threadIdx.x; i < HW; i += 256) outp[i] = h[i];
}

// ---------------------------------------------------------------------------
// Kernel 2: merge histogram partials -> packed deg bytes.
// ---------------------------------------------------------------------------
__global__ __launch_bounds__(256) void k_mdeg(const unsigned int* __restrict__ part,
                                              unsigned int* __restrict__ degb) {
    int w = blockIdx.x * 256 + threadIdx.x;
    int tloc = blockIdx.y;
    if (w >= HW) return;
    const unsigned int* p = part + (size_t)tloc * NSEG_H * HW;
    unsigned int s = 0;
#pragma unroll
    for (int k = 0; k < NSEG_H; k++) s += p[(size_t)k * HW + w];
    degb[(size_t)tloc * HW + w] = s;
}

// ---------------------------------------------------------------------------
// Kernel 3: edge partition, zero global atomics, sentinel-padded regions.
// Record = (src_off<<17)|dst. grid (NSEG_B, tc), 4 waves/block.
// ---------------------------------------------------------------------------
__global__ __launch_bounds__(256) void k_part(const int* __restrict__ ei,
                                              unsigned int* __restrict__ buck, int t0) {
    __shared__ unsigned int stg[4][NCHUNK][WCAP];   // 60 KB
    __shared__ unsigned int cur[4][NCHUNK];         // staged counts
    __shared__ unsigned int gct[4][NCHUNK];         // region write cursors
    int wave = threadIdx.x >> 6, lane = threadIdx.x & 63;
    int tloc = blockIdx.y, tg = t0 + tloc;
    if (lane < 64) { cur[wave][lane] = 0u; gct[wave][lane] = 0u; }
    if (lane < NCHUNK - 64) { cur[wave][64 + lane] = 0u; gct[wave][64 + lane] = 0u; }

    int wseg = blockIdx.x * 4 + wave;               // 0..127
    int e0 = wseg * EPW;
    int e1 = e0 + EPW; if (e1 > EE) e1 = EE;
    const uint4* src4 = (const uint4*)(ei + (size_t)tg * 2 * EE);
    const uint4* dst4 = (const uint4*)(ei + (size_t)tg * 2 * EE + EE);
    // region (tloc, ck, wseg): buck + ((tloc*NCHUNK + ck)*NW + wseg)*RCAP
    unsigned int* bkt = buck + ((size_t)tloc * NCHUNK * NW + wseg) * RCAP;

    int i40 = e0 >> 2, i41 = e1 >> 2;
    int nIter = (i41 - i40 + 63) >> 6;              // wave-uniform
    for (int k = 0; k < nIter; k++) {
        int i4 = i40 + k * 64 + lane;
        if (i4 < i41) {
            uint4 s4 = src4[i4];
            uint4 d4 = dst4[i4];
            unsigned int ss[4] = {s4.x, s4.y, s4.z, s4.w};
            unsigned int dd[4] = {d4.x, d4.y, d4.z, d4.w};
#pragma unroll
            for (int j = 0; j < 4; j++) {
                unsigned int ck = (unsigned int)(((unsigned long long)ss[j] * 4294968ull) >> 32); // /1000
                unsigned int so = ss[j] - ck * NPC;
                unsigned int p = atomicAdd(&cur[wave][ck], 1u);
                if (p < WCAP) stg[wave][ck][p] = (so << 17) | dd[j];
            }
        }
#pragma unroll
        for (int half = 0; half < 2; half++) {
            int nh = half ? (NCHUNK - 64) : 64;
            unsigned int cnt = (lane < nh) ? cur[wave][half * 64 + lane] : 0u;
            unsigned long long mask = __ballot(cnt >= FLUSH_THR);
            while (mask) {
                int ck = half * 64 + (__ffsll((unsigned long long)mask) - 1);
                mask &= mask - 1;
                unsigned int n = cur[wave][ck];
                if (n > WCAP) n = WCAP;
                unsigned int gp = gct[wave][ck];
                unsigned int nw = (gp + n <= RCAP) ? n : ((gp < RCAP) ? (RCAP - gp) : 0u);
                unsigned int* rg = bkt + (size_t)ck * NW * RCAP;
                if (lane < nw) rg[gp + lane] = stg[wave][ck][lane];
                if (lane == 0) { gct[wave][ck] = gp + nw; cur[wave][ck] = 0u; }
            }
        }
    }
    // tail flush + sentinel fill (every slot of every owned region is written)
    unsigned int sv = (1008u + (lane & 15u)) << 17;   // sentinel record
    for (int ck = 0; ck < NCHUNK; ck++) {
        unsigned int n = cur[wave][ck];
        if (n > WCAP) n = WCAP;
        unsigned int gp = gct[wave][ck];              // uniform LDS read
        unsigned int* rg = bkt + (size_t)ck * NW * RCAP;
        unsigned int nw = 0;
        if (n > 0u) {
            nw = (gp + n <= RCAP) ? n : ((gp < RCAP) ? (RCAP - gp) : 0u);
            if (lane < nw) rg[gp + lane] = stg[wave][ck][lane];
        }
        for (unsigned int j = gp + nw + lane; j < RCAP; j += 64)
            rg[j] = sv;
    }
}

// ---------------------------------------------------------------------------
// Kernel 4 (fused): FLAT dense build (no counts, no guards: whole bucket is
// valid records incl. harmless sentinels), pre-fold dinv + self-loop, then
// stream g 4-deep (4KB/wave in flight). grid (NCHUNK, tc), 512 thr, 33KB LDS.
// ---------------------------------------------------------------------------
__global__ __launch_bounds__(512) void k_scat(const float* __restrict__ g,
                                              const unsigned int* __restrict__ degb,
                                              const unsigned int* __restrict__ buck,
                                              float* __restrict__ yp, int t0) {
    __shared__ float a[AROWS * BB];     // 32 KB (rows >=1000 are sentinel trash)
    __shared__ float lut[256];          // 1 KB: rsqrt(deg+1)
    int c = blockIdx.x, tloc = blockIdx.y, tg = t0 + tloc;
    int wave = threadIdx.x >> 6, lane = threadIdx.x & 63;

    for (int i = threadIdx.x; i < AROWS * BB; i += 512) a[i] = 0.0f;
    if (threadIdx.x < 256) lut[threadIdx.x] = rsqrtf((float)threadIdx.x + 1.0f);
    __syncthreads();

    const unsigned char* degc = (const unsigned char*)(degb + (size_t)tloc * HW);
    const unsigned int* bkc = buck + ((size_t)tloc * NCHUNK + c) * NW * RCAP;

    // build: flat dense record array, fully coalesced, deep pipelining
    const uint4* bk4 = (const uint4*)bkc;
    const int NB4 = NW * RCAP / 4;      // 4864 uint4
    for (int i = threadIdx.x; i < NB4; i += 512) {
        uint4 r = bk4[i];
        unsigned int recs[4] = {r.x, r.y, r.z, r.w};
#pragma unroll
        for (int k = 0; k < 4; k++) {
            unsigned int rec = recs[k];
            unsigned int d = rec & 0x1FFFFu;
            unsigned int so = rec >> 17;
            unsigned int b = (unsigned int)(((unsigned long long)d * 429497ull) >> 32); // /10000
            atomicAdd(&a[so * BB + b], lut[degc[d]]);
        }
    }
    __syncthreads();

    // pre-fold: a[j][b] = dinv_j * (a[j][b] + (b==b_c)*dinv_j)   (j < NPC only)
    int b_c = c / 10, coff = c - b_c * 10;
    int jbase = c * NPC;
    for (int j = threadIdx.x; j < NPC; j += 512) {
        float dvj = lut[degc[jbase + j]];
        float* aj = &a[j * BB];
#pragma unroll
        for (int b = 0; b < BB; b++)
            aj[b] = dvj * (aj[b] + (b == b_c ? dvj : 0.0f));
    }
    __syncthreads();

    // stream: 16 lanes per row (float4), 4 rows/wave-load, 4-deep pipelined.
    int sub = lane >> 4;                  // row within group of 4
    int f0 = (lane & 15) << 2;            // float4 feature base
    const float* gbase = g + ((size_t)(b_c * TT + tg) * NNODE + (size_t)coff * NPC) * FF;

    float acc[BB][4];
#pragma unroll
    for (int b = 0; b < BB; b++)
#pragma unroll
        for (int q = 0; q < 4; q++) acc[b][q] = 0.0f;

#define PROC(J, G)                                                          \
    {                                                                       \
        const float4 a0 = *(const float4*)(&a[(J) * BB]);                   \
        const float4 a1 = *(const float4*)(&a[(J) * BB + 4]);               \
        float av[BB] = {a0.x, a0.y, a0.z, a0.w, a1.x, a1.y, a1.z, a1.w};    \
        _Pragma("unroll")                                                   \
        for (int b = 0; b < BB; b++) {                                      \
            acc[b][0] = fmaf((G).x, av[b], acc[b][0]);                      \
            acc[b][1] = fmaf((G).y, av[b], acc[b][1]);                      \
            acc[b][2] = fmaf((G).z, av[b], acc[b][2]);                      \
            acc[b][3] = fmaf((G).w, av[b], acc[b][3]);                      \
        }                                                                   \
    }

    const int NG = NPC / 4;               // 250 groups of 4 rows
    int gi = wave;
    for (; gi + 24 < NG; gi += 32) {
        int j0 = gi * 4 + sub;
        int j1 = (gi + 8) * 4 + sub;
        int j2 = (gi + 16) * 4 + sub;
        int j3 = (gi + 24) * 4 + sub;
        const float4 G0 = *(const float4*)(gbase + (size_t)j0 * FF + f0);
        const float4 G1 = *(const float4*)(gbase + (size_t)j1 * FF + f0);
        const float4 G2 = *(const float4*)(gbase + (size_t)j2 * FF + f0);
        const float4 G3 = *(const float4*)(gbase + (size_t)j3 * FF + f0);
        PROC(j0, G0);
        PROC(j1, G1);
        PROC(j2, G2);
        PROC(j3, G3);
    }
    for (; gi < NG; gi += 8) {
        int j = gi * 4 + sub;
        const float4 G = *(const float4*)(gbase + (size_t)j * FF + f0);
        PROC(j, G);
    }
#undef PROC

    __syncthreads();  // all a reads done; reuse a as scratch[8][512]
#pragma unroll
    for (int b = 0; b < BB; b++)
#pragma unroll
        for (int q = 0; q < 4; q++) {
            float v = acc[b][q];
            v += __shfl_xor(v, 16);
            v += __shfl_xor(v, 32);
            acc[b][q] = v;
        }
    if (sub == 0) {
#pragma unroll
        for (int b = 0; b < BB; b++)
#pragma unroll
            for (int q = 0; q < 4; q++)
                a[wave * (BB * FF) + b * FF + f0 + q] = acc[b][q];
    }
    __syncthreads();
    {
        int idx = threadIdx.x;   // 0..511 = b*64+f
        float s = 0.0f;
#pragma unroll
        for (int w = 0; w < 8; w++) s += a[w * (BB * FF) + idx];
        yp[((size_t)tg * NCHUNK + c) * (BB * FF) + idx] = s;
    }
}

// ---------------------------------------------------------------------------
// Kernel 4c: fold NCHUNK partials -> y2[t][b][f]. grid (TT), 512 threads.
// ---------------------------------------------------------------------------
__global__ __launch_bounds__(512) void k_fold(const float* __restrict__ yp,
                                              float* __restrict__ y2) {
    int t = blockIdx.x;
    int idx = threadIdx.x;   // b*64+f
    const float* p = yp + (size_t)t * NCHUNK * BB * FF + idx;
    float s = 0.0f;
#pragma unroll 8
    for (int u = 0; u < NCHUNK; u++) s += p[(size_t)u * BB * FF];
    y2[(size_t)t * BB * FF + idx] = s;
}

// ---------------------------------------------------------------------------
// Kernel 5: pooled projection + LSTM + FC.
// ---------------------------------------------------------------------------
__global__ __launch_bounds__(256) void k_lstm(const float* __restrict__ y2,
                                              const float* __restrict__ Wg,
                                              const float* __restrict__ bg,
                                              const float* __restrict__ Wih,
                                              const float* __restrict__ Whh,
                                              const float* __restrict__ bih,
                                              const float* __restrict__ bhh,
                                              const float* __restrict__ Wfc,
                                              const float* __restrict__ bfc,
                                              float* __restrict__ out) {
    int b = blockIdx.x;
    int r = threadIdx.x;

    __shared__ float xs[TT][HH];
    __shared__ float hs[HH], cs[HH], zs[4 * HH];

    for (int idx = r; idx < TT * HH; idx += 256) {
        int t = idx >> 6, h = idx & 63;
        const float* yt = y2 + ((size_t)t * BB + b) * FF;
        float s = 0.0f;
#pragma unroll
        for (int f = 0; f < FF; f++) s = fmaf(yt[f], Wg[f * HH + h], s);
        xs[t][h] = s * (1.0f / NNODE) + bg[h];
    }

    float wih[HH], whh[HH];
#pragma unroll
    for (int k = 0; k < HH; k++) {
        wih[k] = Wih[r * HH + k];
        whh[k] = Whh[r * HH + k];
    }
    float bias = bih[r] + bhh[r];

    if (r < HH) { hs[r] = 0.0f; cs[r] = 0.0f; }
    __syncthreads();

    for (int t = 0; t < TT; t++) {
        float acc = bias;
#pragma unroll
        for (int k = 0; k < HH; k++)
            acc = fmaf(wih[k], xs[t][k], fmaf(whh[k], hs[k], acc));
        zs[r] = acc;
        __syncthreads();
        if (r < HH) {
            float iv = zs[r], fv = zs[HH + r], gv = zs[2 * HH + r], ov = zs[3 * HH + r];
            float si = 1.0f / (1.0f + expf(-iv));
            float sf = 1.0f / (1.0f + expf(-fv));
            float so = 1.0f / (1.0f + expf(-ov));
            float cc = sf * cs[r] + si * tanhf(gv);
            cs[r] = cc;
            hs[r] = so * tanhf(cc);
        }
        __syncthreads();
    }

    if (r < NCLS) {
        float s = bfc[r];
#pragma unroll
        for (int k = 0; k < HH; k++) s = fmaf(hs[k], Wfc[r * HH + k], s);
        out[b * NCLS + r] = s;
    }
}

// ---------------------------------------------------------------------------
extern "C" void kernel_launch(void* const* d_in, const int* in_sizes, int n_in,
                              void* d_out, int out_size, void* d_ws, size_t ws_size,
                              hipStream_t stream) {
    const float* g   = (const float*)d_in[0];
    const int*   ei  = (const int*)d_in[1];
    const float* Wg  = (const float*)d_in[2];
    const float* bg  = (const float*)d_in[3];
    const float* Wih = (const float*)d_in[4];
    const float* Whh = (const float*)d_in[5];
    const float* bih = (const float*)d_in[6];
    const float* bhh = (const float*)d_in[7];
    const float* Wfc = (const float*)d_in[8];
    const float* bfc = (const float*)d_in[9];
    float* out = (float*)d_out;

    char* ws = (char*)d_ws;
    float* yp = (float*)ws;                               // [T][NCHUNK][B][F]
    const size_t ypBytes = (size_t)TT * NCHUNK * BB * FF * sizeof(float);  // 2.62 MB
    float* y2 = (float*)(ws + ypBytes);                   // [T][B][F]
    const size_t y2Bytes = (size_t)TT * BB * FF * sizeof(float);           // 64 KB
    const size_t headBytes = ypBytes + y2Bytes;

    const size_t sz_part = (size_t)NSEG_H * HW * 4;        // 1.28 MB
    const size_t sz_degb = (size_t)HW * 4;                 // 80 KB
    const size_t sz_buck = (size_t)NCHUNK * NW * RCAP * 4; // 6.23 MB
    const size_t per_t = sz_part + sz_degb + sz_buck;

    size_t avail = (ws_size > headBytes) ? ws_size - headBytes : 0;
    int Tg = (int)(avail / per_t);
    if (Tg > TT) Tg = TT;
    if (Tg < 1) Tg = 1;

    size_t ofs = headBytes;
    unsigned int* part = (unsigned int*)(ws + ofs); ofs += (size_t)Tg * sz_part;
    unsigned int* degb = (unsigned int*)(ws + ofs); ofs += (size_t)Tg * sz_degb;
    unsigned int* buck = (unsigned int*)(ws + ofs);

    for (int t0 = 0; t0 < TT; t0 += Tg) {
        int tc = (TT - t0 < Tg) ? (TT - t0) : Tg;

        dim3 gh(NSEG_H, tc);
        k_hist<<<gh, 256, 0, stream>>>(ei, part, t0);

        dim3 gm((HW + 255) / 256, tc);
        k_mdeg<<<gm, 256, 0, stream>>>(part, degb);

        dim3 gp(NSEG_B, tc);
        k_part<<<gp, 256, 0, stream>>>(ei, buck, t0);

        dim3 gs(NCHUNK, tc);
        k_scat<<<gs, 512, 0, stream>>>(g, degb, buck, yp, t0);
    }

    k_fold<<<TT, 512, 0, stream>>>(yp, y2);
    k_lstm<<<BB, 256, 0, stream>>>(y2, Wg, bg, Wih, Whh, bih, bhh, Wfc, bfc, out);
}

// Round 13
// 335.724 us; speedup vs baseline: 1.0518x; 1.0518x over previous
//
#include <hip/hip_runtime.h>
#include <hip/hip_bf16.h>

// Problem constants
#define BB 8
#define TT 16
#define NNODE 10000
#define FF 64
#define HH 64
#define EE 1000000
#define MM 80000      // BB * NNODE
#define NCLS 3

#define NCHUNK 80     // src chunks per timestep (10 chunks per graph)
#define NPC 1000      // nodes per chunk
#define NSEG_H 16     // histogram edge segments
#define HW 20000      // histogram words (u8-packed: 4 bins/word = 80000 bins)
#define NSEG_B 32     // k_part blocks per timestep (x4 waves = 128 wave-segments/t)
#define NW 128        // wave-segments per timestep
#define EPW 7816      // edges per wave-segment (mult of 4; 128*7816 >= 1e6)
#define WCAP 48       // wave-private staging capacity per chunk
#define FLUSH_THR 24  // flush when staged count >= this
#define RCAP 152      // records per region (mean 97.7, sigma 9.9 -> 5.5 sigma headroom)
// Record format (self-contained): rec = (so<<11) | (b<<8) | deg
//   so  = src offset within chunk (10 bits, <1000)
//   b   = dst batch (3 bits)
//   deg = degree count of dst (8 bits, max ~50)

// ---------------------------------------------------------------------------
// Kernel 1: per-timestep dst histogram, LDS-privatized, u8-packed, uint4 loads.
// ---------------------------------------------------------------------------
__global__ __launch_bounds__(256) void k_hist(const int* __restrict__ ei,
                                              unsigned int* __restrict__ part, int t0) {
    __shared__ unsigned int h[HW];   // 80 KB
    int seg = blockIdx.x, tloc = blockIdx.y, tg = t0 + tloc;
    for (int i = threadIdx.x; i < HW; i += 256) h[i] = 0u;
    __syncthreads();
    const uint4* dstp = (const uint4*)(ei + (size_t)tg * 2 * EE + EE
                                       + (size_t)seg * (EE / NSEG_H));
    for (int i = threadIdx.x; i < (EE / NSEG_H) / 4; i += 256) {
        uint4 d4 = dstp[i];
        atomicAdd(&h[d4.x >> 2], 1u << ((d4.x & 3u) * 8u));
        atomicAdd(&h[d4.y >> 2], 1u << ((d4.y & 3u) * 8u));
        atomicAdd(&h[d4.z >> 2], 1u << ((d4.z & 3u) * 8u));
        atomicAdd(&h[d4.w >> 2], 1u << ((d4.w & 3u) * 8u));
    }
    __syncthreads();
    unsigned int* outp = part + ((size_t)tloc * NSEG_H + seg) * HW;
    for (int i = threadIdx.x; i < HW; i += 256) outp[i] = h[i];
}

// ---------------------------------------------------------------------------
// Kernel 2: merge histogram partials -> packed deg bytes.
// ---------------------------------------------------------------------------
__global__ __launch_bounds__(256) void k_mdeg(const unsigned int* __restrict__ part,
                                              unsigned int* __restrict__ degb) {
    int w = blockIdx.x * 256 + threadIdx.x;
    int tloc = blockIdx.y;
    if (w >= HW) return;
    const unsigned int* p = part + (size_t)tloc * NSEG_H * HW;
    unsigned int s = 0;
#pragma unroll
    for (int k = 0; k < NSEG_H; k++) s += p[(size_t)k * HW + w];
    degb[(size_t)tloc * HW + w] = s;
}

// ---------------------------------------------------------------------------
// Kernel 3: edge partition, zero global atomics, headerless regions + hdr
// array. Gathers deg byte per edge (4 independent chains/lane) and packs
// self-contained records. grid (NSEG_B, tc), 4 waves/block.
// ---------------------------------------------------------------------------
__global__ __launch_bounds__(256) void k_part(const int* __restrict__ ei,
                                              const unsigned int* __restrict__ degb,
                                              unsigned int* __restrict__ buck,
                                              unsigned int* __restrict__ hdr, int t0) {
    __shared__ unsigned int stg[4][NCHUNK][WCAP];   // 60 KB
    __shared__ unsigned int cur[4][NCHUNK];         // staged counts
    __shared__ unsigned int gct[4][NCHUNK];         // region write cursors
    int wave = threadIdx.x >> 6, lane = threadIdx.x & 63;
    int tloc = blockIdx.y, tg = t0 + tloc;
    if (lane < 64) { cur[wave][lane] = 0u; gct[wave][lane] = 0u; }
    if (lane < NCHUNK - 64) { cur[wave][64 + lane] = 0u; gct[wave][64 + lane] = 0u; }

    int wseg = blockIdx.x * 4 + wave;               // 0..127
    int e0 = wseg * EPW;
    int e1 = e0 + EPW; if (e1 > EE) e1 = EE;
    const uint4* src4 = (const uint4*)(ei + (size_t)tg * 2 * EE);
    const uint4* dst4 = (const uint4*)(ei + (size_t)tg * 2 * EE + EE);
    const unsigned char* degc = (const unsigned char*)(degb + (size_t)tloc * HW);
    unsigned int* bkt = buck + ((size_t)tloc * NCHUNK * NW + wseg) * RCAP;

    int i40 = e0 >> 2, i41 = e1 >> 2;
    int nIter = (i41 - i40 + 63) >> 6;              // wave-uniform
    for (int k = 0; k < nIter; k++) {
        int i4 = i40 + k * 64 + lane;
        if (i4 < i41) {
            uint4 s4 = src4[i4];
            uint4 d4 = dst4[i4];
            unsigned int ss[4] = {s4.x, s4.y, s4.z, s4.w};
            unsigned int dd[4] = {d4.x, d4.y, d4.z, d4.w};
            // issue 4 independent deg gathers first (hide under cursor work)
            unsigned int dg[4];
#pragma unroll
            for (int j = 0; j < 4; j++) dg[j] = degc[dd[j]];
#pragma unroll
            for (int j = 0; j < 4; j++) {
                unsigned int ck = (unsigned int)(((unsigned long long)ss[j] * 4294968ull) >> 32); // /1000
                unsigned int so = ss[j] - ck * NPC;
                unsigned int b  = (unsigned int)(((unsigned long long)dd[j] * 429497ull) >> 32);  // /10000
                unsigned int p = atomicAdd(&cur[wave][ck], 1u);
                if (p < WCAP) stg[wave][ck][p] = (so << 11) | (b << 8) | dg[j];
            }
        }
#pragma unroll
        for (int half = 0; half < 2; half++) {
            int nh = half ? (NCHUNK - 64) : 64;
            unsigned int cnt = (lane < nh) ? cur[wave][half * 64 + lane] : 0u;
            unsigned long long mask = __ballot(cnt >= FLUSH_THR);
            while (mask) {
                int ck = half * 64 + (__ffsll((unsigned long long)mask) - 1);
                mask &= mask - 1;
                unsigned int n = cur[wave][ck];
                if (n > WCAP) n = WCAP;
                unsigned int gp = gct[wave][ck];
                unsigned int nw = (gp + n <= RCAP) ? n : ((gp < RCAP) ? (RCAP - gp) : 0u);
                unsigned int* rg = bkt + (size_t)ck * NW * RCAP;
                if (lane < nw) rg[gp + lane] = stg[wave][ck][lane];
                if (lane == 0) { gct[wave][ck] = gp + nw; cur[wave][ck] = 0u; }
            }
        }
    }
    // tail flush
    for (int ck = 0; ck < NCHUNK; ck++) {
        unsigned int n = cur[wave][ck];
        if (n > WCAP) n = WCAP;
        if (n > 0u) {
            unsigned int gp = gct[wave][ck];
            unsigned int nw = (gp + n <= RCAP) ? n : ((gp < RCAP) ? (RCAP - gp) : 0u);
            unsigned int* rg = bkt + (size_t)ck * NW * RCAP;
            if (lane < nw) rg[gp + lane] = stg[wave][ck][lane];
            if (lane == 0) gct[wave][ck] = gp + nw;
        }
    }
    // write counts to header array (coalesced per wave)
    for (int ck = lane; ck < NCHUNK; ck += 64)
        hdr[((size_t)tloc * NCHUNK + ck) * NW + wseg] = gct[wave][ck];
}

// ---------------------------------------------------------------------------
// Kernel 4 (fused): build a[src][b] in LDS from SELF-CONTAINED records
// (coalesced uint4 load -> VALU decode + v_rsq -> ds_add; no gathers, no LUT,
// no load-load chains), pre-fold dinv + self-loop, then stream g with float4
// loads 2-deep. grid (NCHUNK, tc), 512 thr, ~32 KB LDS -> 4+ blocks/CU.
// ---------------------------------------------------------------------------
__global__ __launch_bounds__(512) void k_scat(const float* __restrict__ g,
                                              const unsigned int* __restrict__ degb,
                                              const unsigned int* __restrict__ buck,
                                              const unsigned int* __restrict__ hdr,
                                              float* __restrict__ yp, int t0) {
    __shared__ float a[NPC * BB];       // 31.25 KB (reused as reduction scratch)
    __shared__ unsigned int hcnt[NW];   // 0.5 KB region counts
    int c = blockIdx.x, tloc = blockIdx.y, tg = t0 + tloc;
    int wave = threadIdx.x >> 6, lane = threadIdx.x & 63;

    for (int i = threadIdx.x; i < NPC * BB; i += 512) a[i] = 0.0f;
    if (threadIdx.x < NW)
        hcnt[threadIdx.x] = hdr[((size_t)tloc * NCHUNK + c) * NW + threadIdx.x];
    __syncthreads();

    const unsigned int* bkc = buck + ((size_t)tloc * NCHUNK + c) * NW * RCAP;

    // build: 8 waves x 16 regions; one uint4 wave-load covers a whole region.
    // Per record: VALU decode + rsqrt + LDS atomic. Zero dependent loads.
    for (int r = wave; r < NW; r += 8) {
        unsigned int cnt = hcnt[r];
        if (cnt > RCAP) cnt = RCAP;
        const uint4* rg4 = (const uint4*)(bkc + (size_t)r * RCAP);
        unsigned int i0 = lane << 2;
        if (i0 < cnt) {
            uint4 rr = rg4[lane];
            unsigned int recs[4] = {rr.x, rr.y, rr.z, rr.w};
#pragma unroll
            for (int k = 0; k < 4; k++) {
                if (i0 + (unsigned)k < cnt) {
                    unsigned int rec = recs[k];
                    unsigned int so = rec >> 11;
                    unsigned int b  = (rec >> 8) & 7u;
                    float dv = rsqrtf((float)(rec & 255u) + 1.0f);
                    atomicAdd(&a[so * BB + b], dv);
                }
            }
        }
    }
    __syncthreads();

    // pre-fold: a[j][b] = dinv_j * (a[j][b] + (b==b_c)*dinv_j)
    const unsigned char* degc = (const unsigned char*)(degb + (size_t)tloc * HW);
    int b_c = c / 10, coff = c - b_c * 10;
    int jbase = c * NPC;
    for (int j = threadIdx.x; j < NPC; j += 512) {
        float dvj = rsqrtf((float)degc[jbase + j] + 1.0f);   // coalesced byte read
        float* aj = &a[j * BB];
#pragma unroll
        for (int b = 0; b < BB; b++)
            aj[b] = dvj * (aj[b] + (b == b_c ? dvj : 0.0f));
    }
    __syncthreads();

    // stream: 16 lanes per row (float4), 4 rows/wave-load, 2-deep.
    int sub = lane >> 4;                  // row within group of 4
    int f0 = (lane & 15) << 2;            // float4 feature base
    const float* gbase = g + ((size_t)(b_c * TT + tg) * NNODE + (size_t)coff * NPC) * FF;

    float acc[BB][4];
#pragma unroll
    for (int b = 0; b < BB; b++)
#pragma unroll
        for (int q = 0; q < 4; q++) acc[b][q] = 0.0f;

    const int NG = NPC / 4;               // 250 groups of 4 rows
    for (int gi = wave; gi < NG; gi += 16) {
        int j0 = gi * 4 + sub;
        int gi1 = gi + 8;
        int j1 = gi1 * 4 + sub;
        bool h1 = (gi1 < NG);
        const float4 g40 = *(const float4*)(gbase + (size_t)j0 * FF + f0);
        float4 g41 = h1 ? *(const float4*)(gbase + (size_t)j1 * FF + f0)
                        : make_float4(0.f, 0.f, 0.f, 0.f);
        {
            const float4 a0 = *(const float4*)(&a[j0 * BB]);
            const float4 a1 = *(const float4*)(&a[j0 * BB + 4]);
            float av[BB] = {a0.x, a0.y, a0.z, a0.w, a1.x, a1.y, a1.z, a1.w};
#pragma unroll
            for (int b = 0; b < BB; b++) {
                acc[b][0] = fmaf(g40.x, av[b], acc[b][0]);
                acc[b][1] = fmaf(g40.y, av[b], acc[b][1]);
                acc[b][2] = fmaf(g40.z, av[b], acc[b][2]);
                acc[b][3] = fmaf(g40.w, av[b], acc[b][3]);
            }
        }
        if (h1) {
            const float4 a0 = *(const float4*)(&a[j1 * BB]);
            const float4 a1 = *(const float4*)(&a[j1 * BB + 4]);
            float av[BB] = {a0.x, a0.y, a0.z, a0.w, a1.x, a1.y, a1.z, a1.w};
#pragma unroll
            for (int b = 0; b < BB; b++) {
                acc[b][0] = fmaf(g41.x, av[b], acc[b][0]);
                acc[b][1] = fmaf(g41.y, av[b], acc[b][1]);
                acc[b][2] = fmaf(g41.z, av[b], acc[b][2]);
                acc[b][3] = fmaf(g41.w, av[b], acc[b][3]);
            }
        }
    }

    __syncthreads();  // all a reads done; reuse a as scratch[8][512]
#pragma unroll
    for (int b = 0; b < BB; b++)
#pragma unroll
        for (int q = 0; q < 4; q++) {
            float v = acc[b][q];
            v += __shfl_xor(v, 16);
            v += __shfl_xor(v, 32);
            acc[b][q] = v;
        }
    if (sub == 0) {
#pragma unroll
        for (int b = 0; b < BB; b++)
#pragma unroll
            for (int q = 0; q < 4; q++)
                a[wave * (BB * FF) + b * FF + f0 + q] = acc[b][q];
    }
    __syncthreads();
    {
        int idx = threadIdx.x;   // 0..511 = b*64+f
        float s = 0.0f;
#pragma unroll
        for (int w = 0; w < 8; w++) s += a[w * (BB * FF) + idx];
        yp[((size_t)tg * NCHUNK + c) * (BB * FF) + idx] = s;
    }
}

// ---------------------------------------------------------------------------
// Kernel 4c: fold NCHUNK partials -> y2[t][b][f]. grid (TT), 512 threads.
// ---------------------------------------------------------------------------
__global__ __launch_bounds__(512) void k_fold(const float* __restrict__ yp,
                                              float* __restrict__ y2) {
    int t = blockIdx.x;
    int idx = threadIdx.x;   // b*64+f
    const float* p = yp + (size_t)t * NCHUNK * BB * FF + idx;
    float s = 0.0f;
#pragma unroll 8
    for (int u = 0; u < NCHUNK; u++) s += p[(size_t)u * BB * FF];
    y2[(size_t)t * BB * FF + idx] = s;
}

// ---------------------------------------------------------------------------
// Kernel 5: pooled projection + LSTM + FC.
// ---------------------------------------------------------------------------
__global__ __launch_bounds__(256) void k_lstm(const float* __restrict__ y2,
                                              const float* __restrict__ Wg,
                                              const float* __restrict__ bg,
                                              const float* __restrict__ Wih,
                                              const float* __restrict__ Whh,
                                              const float* __restrict__ bih,
                                              const float* __restrict__ bhh,
                                              const float* __restrict__ Wfc,
                                              const float* __restrict__ bfc,
                                              float* __restrict__ out) {
    int b = blockIdx.x;
    int r = threadIdx.x;

    __shared__ float xs[TT][HH];
    __shared__ float hs[HH], cs[HH], zs[4 * HH];

    for (int idx = r; idx < TT * HH; idx += 256) {
        int t = idx >> 6, h = idx & 63;
        const float* yt = y2 + ((size_t)t * BB + b) * FF;
        float s = 0.0f;
#pragma unroll
        for (int f = 0; f < FF; f++) s = fmaf(yt[f], Wg[f * HH + h], s);
        xs[t][h] = s * (1.0f / NNODE) + bg[h];
    }

    float wih[HH], whh[HH];
#pragma unroll
    for (int k = 0; k < HH; k++) {
        wih[k] = Wih[r * HH + k];
        whh[k] = Whh[r * HH + k];
    }
    float bias = bih[r] + bhh[r];

    if (r < HH) { hs[r] = 0.0f; cs[r] = 0.0f; }
    __syncthreads();

    for (int t = 0; t < TT; t++) {
        float acc = bias;
#pragma unroll
        for (int k = 0; k < HH; k++)
            acc = fmaf(wih[k], xs[t][k], fmaf(whh[k], hs[k], acc));
        zs[r] = acc;
        __syncthreads();
        if (r < HH) {
            float iv = zs[r], fv = zs[HH + r], gv = zs[2 * HH + r], ov = zs[3 * HH + r];
            float si = 1.0f / (1.0f + expf(-iv));
            float sf = 1.0f / (1.0f + expf(-fv));
            float so = 1.0f / (1.0f + expf(-ov));
            float cc = sf * cs[r] + si * tanhf(gv);
            cs[r] = cc;
            hs[r] = so * tanhf(cc);
        }
        __syncthreads();
    }

    if (r < NCLS) {
        float s = bfc[r];
#pragma unroll
        for (int k = 0; k < HH; k++) s = fmaf(hs[k], Wfc[r * HH + k], s);
        out[b * NCLS + r] = s;
    }
}

// ---------------------------------------------------------------------------
extern "C" void kernel_launch(void* const* d_in, const int* in_sizes, int n_in,
                              void* d_out, int out_size, void* d_ws, size_t ws_size,
                              hipStream_t stream) {
    const float* g   = (const float*)d_in[0];
    const int*   ei  = (const int*)d_in[1];
    const float* Wg  = (const float*)d_in[2];
    const float* bg  = (const float*)d_in[3];
    const float* Wih = (const float*)d_in[4];
    const float* Whh = (const float*)d_in[5];
    const float* bih = (const float*)d_in[6];
    const float* bhh = (const float*)d_in[7];
    const float* Wfc = (const float*)d_in[8];
    const float* bfc = (const float*)d_in[9];
    float* out = (float*)d_out;

    char* ws = (char*)d_ws;
    float* yp = (float*)ws;                               // [T][NCHUNK][B][F]
    const size_t ypBytes = (size_t)TT * NCHUNK * BB * FF * sizeof(float);  // 2.62 MB
    float* y2 = (float*)(ws + ypBytes);                   // [T][B][F]
    const size_t y2Bytes = (size_t)TT * BB * FF * sizeof(float);           // 64 KB
    const size_t headBytes = ypBytes + y2Bytes;

    const size_t sz_part = (size_t)NSEG_H * HW * 4;        // 1.28 MB
    const size_t sz_degb = (size_t)HW * 4;                 // 80 KB
    const size_t sz_buck = (size_t)NCHUNK * NW * RCAP * 4; // 6.23 MB
    const size_t sz_hdr  = (size_t)NCHUNK * NW * 4;        // 41 KB
    const size_t per_t = sz_part + sz_degb + sz_buck + sz_hdr;

    size_t avail = (ws_size > headBytes) ? ws_size - headBytes : 0;
    int Tg = (int)(avail / per_t);
    if (Tg > TT) Tg = TT;
    if (Tg < 1) Tg = 1;

    size_t ofs = headBytes;
    unsigned int* part = (unsigned int*)(ws + ofs); ofs += (size_t)Tg * sz_part;
    unsigned int* degb = (unsigned int*)(ws + ofs); ofs += (size_t)Tg * sz_degb;
    unsigned int* hdr  = (unsigned int*)(ws + ofs); ofs += (size_t)Tg * sz_hdr;
    unsigned int* buck = (unsigned int*)(ws + ofs);

    for (int t0 = 0; t0 < TT; t0 += Tg) {
        int tc = (TT - t0 < Tg) ? (TT - t0) : Tg;

        dim3 gh(NSEG_H, tc);
        k_hist<<<gh, 256, 0, stream>>>(ei, part, t0);

        dim3 gm((HW + 255) / 256, tc);
        k_mdeg<<<gm, 256, 0, stream>>>(part, degb);

        dim3 gp(NSEG_B, tc);
        k_part<<<gp, 256, 0, stream>>>(ei, degb, buck, hdr, t0);

        dim3 gs(NCHUNK, tc);
        k_scat<<<gs, 512, 0, stream>>>(g, degb, buck, hdr, yp, t0);
    }

    k_fold<<<TT, 512, 0, stream>>>(yp, y2);
    k_lstm<<<BB, 256, 0, stream>>>(y2, Wg, bg, Wih, Whh, bih, bhh, Wfc, bfc, out);
}

// Round 14
// 313.202 us; speedup vs baseline: 1.1274x; 1.0719x over previous
//
#include <hip/hip_runtime.h>
#include <hip/hip_bf16.h>

// Problem constants
#define BB 8
#define TT 16
#define NNODE 10000
#define FF 64
#define HH 64
#define EE 1000000
#define MM 80000      // BB * NNODE
#define NCLS 3

#define NCHUNK 80     // src chunks per timestep (10 chunks per graph)
#define NPC 1000      // nodes per chunk
#define NSEG_H 16     // histogram edge segments
#define HW 20000      // histogram words (u8-packed: 4 bins/word = 80000 bins)
#define NSEG_B 32     // k_part blocks per timestep (x4 waves = 128 wave-segments/t)
#define NW 128        // wave-segments per timestep
#define EPW 7816      // edges per wave-segment (mult of 4; 128*7816 >= 1e6)
#define WCAP 56       // wave-private staging capacity per chunk
#define FLUSH_THR 32  // flush when staged count >= this (headroom 24 = R11's margin)
#define RCAP 152      // records per region (mean 97.7, sigma 9.9 -> 5.5 sigma headroom)
// Record format (R11, measured best): rec = (so<<17) | dst
//   so  = src offset within chunk (10 bits, <1000), dst = global node (17 bits)

// ---------------------------------------------------------------------------
// Kernel 1: per-timestep dst histogram, LDS-privatized, u8-packed, uint4 loads.
// ---------------------------------------------------------------------------
__global__ __launch_bounds__(256) void k_hist(const int* __restrict__ ei,
                                              unsigned int* __restrict__ part, int t0) {
    __shared__ unsigned int h[HW];   // 80 KB
    int seg = blockIdx.x, tloc = blockIdx.y, tg = t0 + tloc;
    for (int i = threadIdx.x; i < HW; i += 256) h[i] = 0u;
    __syncthreads();
    const uint4* dstp = (const uint4*)(ei + (size_t)tg * 2 * EE + EE
                                       + (size_t)seg * (EE / NSEG_H));
    for (int i = threadIdx.x; i < (EE / NSEG_H) / 4; i += 256) {
        uint4 d4 = dstp[i];
        atomicAdd(&h[d4.x >> 2], 1u << ((d4.x & 3u) * 8u));
        atomicAdd(&h[d4.y >> 2], 1u << ((d4.y & 3u) * 8u));
        atomicAdd(&h[d4.z >> 2], 1u << ((d4.z & 3u) * 8u));
        atomicAdd(&h[d4.w >> 2], 1u << ((d4.w & 3u) * 8u));
    }
    __syncthreads();
    unsigned int* outp = part + ((size_t)tloc * NSEG_H + seg) * HW;
    for (int i = threadIdx.x; i < HW; i += 256) outp[i] = h[i];
}

// ---------------------------------------------------------------------------
// Kernel 2: merge histogram partials -> packed deg bytes.
// ---------------------------------------------------------------------------
__global__ __launch_bounds__(256) void k_mdeg(const unsigned int* __restrict__ part,
                                              unsigned int* __restrict__ degb) {
    int w = blockIdx.x * 256 + threadIdx.x;
    int tloc = blockIdx.y;
    if (w >= HW) return;
    const unsigned int* p = part + (size_t)tloc * NSEG_H * HW;
    unsigned int s = 0;
#pragma unroll
    for (int k = 0; k < NSEG_H; k++) s += p[(size_t)k * HW + w];
    degb[(size_t)tloc * HW + w] = s;
}

// ---------------------------------------------------------------------------
// Kernel 3: edge partition, zero global atomics, headerless regions + hdr
// array. Record = (so<<17)|dst. grid (NSEG_B, tc), 4 waves/block.
// WCAP=56/FLUSH=32: fuller flush bursts, ~25% fewer ballot iterations.
// ---------------------------------------------------------------------------
__global__ __launch_bounds__(256) void k_part(const int* __restrict__ ei,
                                              unsigned int* __restrict__ buck,
                                              unsigned int* __restrict__ hdr, int t0) {
    __shared__ unsigned int stg[4][NCHUNK][WCAP];   // 71.7 KB
    __shared__ unsigned int cur[4][NCHUNK];         // staged counts
    __shared__ unsigned int gct[4][NCHUNK];         // region write cursors
    int wave = threadIdx.x >> 6, lane = threadIdx.x & 63;
    int tloc = blockIdx.y, tg = t0 + tloc;
    if (lane < 64) { cur[wave][lane] = 0u; gct[wave][lane] = 0u; }
    if (lane < NCHUNK - 64) { cur[wave][64 + lane] = 0u; gct[wave][64 + lane] = 0u; }

    int wseg = blockIdx.x * 4 + wave;               // 0..127
    int e0 = wseg * EPW;
    int e1 = e0 + EPW; if (e1 > EE) e1 = EE;
    const uint4* src4 = (const uint4*)(ei + (size_t)tg * 2 * EE);
    const uint4* dst4 = (const uint4*)(ei + (size_t)tg * 2 * EE + EE);
    unsigned int* bkt = buck + ((size_t)tloc * NCHUNK * NW + wseg) * RCAP;

    int i40 = e0 >> 2, i41 = e1 >> 2;
    int nIter = (i41 - i40 + 63) >> 6;              // wave-uniform
    for (int k = 0; k < nIter; k++) {
        int i4 = i40 + k * 64 + lane;
        if (i4 < i41) {
            uint4 s4 = src4[i4];
            uint4 d4 = dst4[i4];
            unsigned int ss[4] = {s4.x, s4.y, s4.z, s4.w};
            unsigned int dd[4] = {d4.x, d4.y, d4.z, d4.w};
#pragma unroll
            for (int j = 0; j < 4; j++) {
                unsigned int ck = (unsigned int)(((unsigned long long)ss[j] * 4294968ull) >> 32); // /1000
                unsigned int so = ss[j] - ck * NPC;
                unsigned int p = atomicAdd(&cur[wave][ck], 1u);
                if (p < WCAP) stg[wave][ck][p] = (so << 17) | dd[j];
            }
        }
#pragma unroll
        for (int half = 0; half < 2; half++) {
            int nh = half ? (NCHUNK - 64) : 64;
            unsigned int cnt = (lane < nh) ? cur[wave][half * 64 + lane] : 0u;
            unsigned long long mask = __ballot(cnt >= FLUSH_THR);
            while (mask) {
                int ck = half * 64 + (__ffsll((unsigned long long)mask) - 1);
                mask &= mask - 1;
                unsigned int n = cur[wave][ck];
                if (n > WCAP) n = WCAP;
                unsigned int gp = gct[wave][ck];
                unsigned int nw = (gp + n <= RCAP) ? n : ((gp < RCAP) ? (RCAP - gp) : 0u);
                unsigned int* rg = bkt + (size_t)ck * NW * RCAP;
                if (lane < nw) rg[gp + lane] = stg[wave][ck][lane];
                if (lane == 0) { gct[wave][ck] = gp + nw; cur[wave][ck] = 0u; }
            }
        }
    }
    // tail flush
    for (int ck = 0; ck < NCHUNK; ck++) {
        unsigned int n = cur[wave][ck];
        if (n > WCAP) n = WCAP;
        if (n > 0u) {
            unsigned int gp = gct[wave][ck];
            unsigned int nw = (gp + n <= RCAP) ? n : ((gp < RCAP) ? (RCAP - gp) : 0u);
            unsigned int* rg = bkt + (size_t)ck * NW * RCAP;
            if (lane < nw) rg[gp + lane] = stg[wave][ck][lane];
            if (lane == 0) gct[wave][ck] = gp + nw;
        }
    }
    // write counts to header array (coalesced per wave)
    for (int ck = lane; ck < NCHUNK; ck += 64)
        hdr[((size_t)tloc * NCHUNK + ck) * NW + wseg] = gct[wave][ck];
}

// ---------------------------------------------------------------------------
// Kernel 4 (fused, R11-verified): preload 128 region counts, build a[src][b]
// in LDS with uint4 record reads + LUT deg-gather, pre-fold dinv + self-loop,
// then stream g with float4 loads 2-deep. grid (NCHUNK, tc), 512 thr, 33.5 KB.
// ---------------------------------------------------------------------------
__global__ __launch_bounds__(512) void k_scat(const float* __restrict__ g,
                                              const unsigned int* __restrict__ degb,
                                              const unsigned int* __restrict__ buck,
                                              const unsigned int* __restrict__ hdr,
                                              float* __restrict__ yp, int t0) {
    __shared__ float a[NPC * BB];       // 32 KB (reused as reduction scratch)
    __shared__ float lut[256];          // 1 KB: rsqrt(deg+1)
    __shared__ unsigned int hcnt[NW];   // 0.5 KB region counts
    int c = blockIdx.x, tloc = blockIdx.y, tg = t0 + tloc;
    int wave = threadIdx.x >> 6, lane = threadIdx.x & 63;

    for (int i = threadIdx.x; i < NPC * BB; i += 512) a[i] = 0.0f;
    if (threadIdx.x < 256) lut[threadIdx.x] = rsqrtf((float)threadIdx.x + 1.0f);
    if (threadIdx.x < NW)
        hcnt[threadIdx.x] = hdr[((size_t)tloc * NCHUNK + c) * NW + threadIdx.x];
    __syncthreads();

    const unsigned char* degc = (const unsigned char*)(degb + (size_t)tloc * HW);
    const unsigned int* bkc = buck + ((size_t)tloc * NCHUNK + c) * NW * RCAP;

    // build: 8 waves x 16 regions; one uint4 wave-load covers a whole region
    for (int r = wave; r < NW; r += 8) {
        unsigned int cnt = hcnt[r];
        if (cnt > RCAP) cnt = RCAP;
        const uint4* rg4 = (const uint4*)(bkc + (size_t)r * RCAP);
        unsigned int i0 = lane << 2;
        if (i0 < cnt) {
            uint4 rr = rg4[lane];
            unsigned int recs[4] = {rr.x, rr.y, rr.z, rr.w};
#pragma unroll
            for (int k = 0; k < 4; k++) {
                if (i0 + (unsigned)k < cnt) {
                    unsigned int rec = recs[k];
                    unsigned int d = rec & 0x1FFFFu;
                    unsigned int so = rec >> 17;
                    unsigned int b = (unsigned int)(((unsigned long long)d * 429497ull) >> 32); // /10000
                    atomicAdd(&a[so * BB + b], lut[degc[d]]);
                }
            }
        }
    }
    __syncthreads();

    // pre-fold: a[j][b] = dinv_j * (a[j][b] + (b==b_c)*dinv_j)
    int b_c = c / 10, coff = c - b_c * 10;
    int jbase = c * NPC;
    for (int j = threadIdx.x; j < NPC; j += 512) {
        float dvj = lut[degc[jbase + j]];
        float* aj = &a[j * BB];
#pragma unroll
        for (int b = 0; b < BB; b++)
            aj[b] = dvj * (aj[b] + (b == b_c ? dvj : 0.0f));
    }
    __syncthreads();

    // stream: 16 lanes per row (float4), 4 rows/wave-load, 2-deep.
    int sub = lane >> 4;                  // row within group of 4
    int f0 = (lane & 15) << 2;            // float4 feature base
    const float* gbase = g + ((size_t)(b_c * TT + tg) * NNODE + (size_t)coff * NPC) * FF;

    float acc[BB][4];
#pragma unroll
    for (int b = 0; b < BB; b++)
#pragma unroll
        for (int q = 0; q < 4; q++) acc[b][q] = 0.0f;

    const int NG = NPC / 4;               // 250 groups of 4 rows
    for (int gi = wave; gi < NG; gi += 16) {
        int j0 = gi * 4 + sub;
        int gi1 = gi + 8;
        int j1 = gi1 * 4 + sub;
        bool h1 = (gi1 < NG);
        const float4 g40 = *(const float4*)(gbase + (size_t)j0 * FF + f0);
        float4 g41 = h1 ? *(const float4*)(gbase + (size_t)j1 * FF + f0)
                        : make_float4(0.f, 0.f, 0.f, 0.f);
        {
            const float4 a0 = *(const float4*)(&a[j0 * BB]);
            const float4 a1 = *(const float4*)(&a[j0 * BB + 4]);
            float av[BB] = {a0.x, a0.y, a0.z, a0.w, a1.x, a1.y, a1.z, a1.w};
#pragma unroll
            for (int b = 0; b < BB; b++) {
                acc[b][0] = fmaf(g40.x, av[b], acc[b][0]);
                acc[b][1] = fmaf(g40.y, av[b], acc[b][1]);
                acc[b][2] = fmaf(g40.z, av[b], acc[b][2]);
                acc[b][3] = fmaf(g40.w, av[b], acc[b][3]);
            }
        }
        if (h1) {
            const float4 a0 = *(const float4*)(&a[j1 * BB]);
            const float4 a1 = *(const float4*)(&a[j1 * BB + 4]);
            float av[BB] = {a0.x, a0.y, a0.z, a0.w, a1.x, a1.y, a1.z, a1.w};
#pragma unroll
            for (int b = 0; b < BB; b++) {
                acc[b][0] = fmaf(g41.x, av[b], acc[b][0]);
                acc[b][1] = fmaf(g41.y, av[b], acc[b][1]);
                acc[b][2] = fmaf(g41.z, av[b], acc[b][2]);
                acc[b][3] = fmaf(g41.w, av[b], acc[b][3]);
            }
        }
    }

    __syncthreads();  // all a reads done; reuse a as scratch[8][512]
#pragma unroll
    for (int b = 0; b < BB; b++)
#pragma unroll
        for (int q = 0; q < 4; q++) {
            float v = acc[b][q];
            v += __shfl_xor(v, 16);
            v += __shfl_xor(v, 32);
            acc[b][q] = v;
        }
    if (sub == 0) {
#pragma unroll
        for (int b = 0; b < BB; b++)
#pragma unroll
            for (int q = 0; q < 4; q++)
                a[wave * (BB * FF) + b * FF + f0 + q] = acc[b][q];
    }
    __syncthreads();
    {
        int idx = threadIdx.x;   // 0..511 = b*64+f
        float s = 0.0f;
#pragma unroll
        for (int w = 0; w < 8; w++) s += a[w * (BB * FF) + idx];
        yp[((size_t)tg * NCHUNK + c) * (BB * FF) + idx] = s;
    }
}

// ---------------------------------------------------------------------------
// Kernel 4c: fold NCHUNK partials -> y2[t][b][f]. grid (TT), 512 threads.
// ---------------------------------------------------------------------------
__global__ __launch_bounds__(512) void k_fold(const float* __restrict__ yp,
                                              float* __restrict__ y2) {
    int t = blockIdx.x;
    int idx = threadIdx.x;   // b*64+f
    const float* p = yp + (size_t)t * NCHUNK * BB * FF + idx;
    float s = 0.0f;
#pragma unroll 8
    for (int u = 0; u < NCHUNK; u++) s += p[(size_t)u * BB * FF];
    y2[(size_t)t * BB * FF + idx] = s;
}

// ---------------------------------------------------------------------------
// Kernel 5: pooled projection + LSTM + FC.
// ---------------------------------------------------------------------------
__global__ __launch_bounds__(256) void k_lstm(const float* __restrict__ y2,
                                              const float* __restrict__ Wg,
                                              const float* __restrict__ bg,
                                              const float* __restrict__ Wih,
                                              const float* __restrict__ Whh,
                                              const float* __restrict__ bih,
                                              const float* __restrict__ bhh,
                                              const float* __restrict__ Wfc,
                                              const float* __restrict__ bfc,
                                              float* __restrict__ out) {
    int b = blockIdx.x;
    int r = threadIdx.x;

    __shared__ float xs[TT][HH];
    __shared__ float hs[HH], cs[HH], zs[4 * HH];

    for (int idx = r; idx < TT * HH; idx += 256) {
        int t = idx >> 6, h = idx & 63;
        const float* yt = y2 + ((size_t)t * BB + b) * FF;
        float s = 0.0f;
#pragma unroll
        for (int f = 0; f < FF; f++) s = fmaf(yt[f], Wg[f * HH + h], s);
        xs[t][h] = s * (1.0f / NNODE) + bg[h];
    }

    float wih[HH], whh[HH];
#pragma unroll
    for (int k = 0; k < HH; k++) {
        wih[k] = Wih[r * HH + k];
        whh[k] = Whh[r * HH + k];
    }
    float bias = bih[r] + bhh[r];

    if (r < HH) { hs[r] = 0.0f; cs[r] = 0.0f; }
    __syncthreads();

    for (int t = 0; t < TT; t++) {
        float acc = bias;
#pragma unroll
        for (int k = 0; k < HH; k++)
            acc = fmaf(wih[k], xs[t][k], fmaf(whh[k], hs[k], acc));
        zs[r] = acc;
        __syncthreads();
        if (r < HH) {
            float iv = zs[r], fv = zs[HH + r], gv = zs[2 * HH + r], ov = zs[3 * HH + r];
            float si = 1.0f / (1.0f + expf(-iv));
            float sf = 1.0f / (1.0f + expf(-fv));
            float so = 1.0f / (1.0f + expf(-ov));
            float cc = sf * cs[r] + si * tanhf(gv);
            cs[r] = cc;
            hs[r] = so * tanhf(cc);
        }
        __syncthreads();
    }

    if (r < NCLS) {
        float s = bfc[r];
#pragma unroll
        for (int k = 0; k < HH; k++) s = fmaf(hs[k], Wfc[r * HH + k], s);
        out[b * NCLS + r] = s;
    }
}

// ---------------------------------------------------------------------------
extern "C" void kernel_launch(void* const* d_in, const int* in_sizes, int n_in,
                              void* d_out, int out_size, void* d_ws, size_t ws_size,
                              hipStream_t stream) {
    const float* g   = (const float*)d_in[0];
    const int*   ei  = (const int*)d_in[1];
    const float* Wg  = (const float*)d_in[2];
    const float* bg  = (const float*)d_in[3];
    const float* Wih = (const float*)d_in[4];
    const float* Whh = (const float*)d_in[5];
    const float* bih = (const float*)d_in[6];
    const float* bhh = (const float*)d_in[7];
    const float* Wfc = (const float*)d_in[8];
    const float* bfc = (const float*)d_in[9];
    float* out = (float*)d_out;

    char* ws = (char*)d_ws;
    float* yp = (float*)ws;                               // [T][NCHUNK][B][F]
    const size_t ypBytes = (size_t)TT * NCHUNK * BB * FF * sizeof(float);  // 2.62 MB
    float* y2 = (float*)(ws + ypBytes);                   // [T][B][F]
    const size_t y2Bytes = (size_t)TT * BB * FF * sizeof(float);           // 64 KB
    const size_t headBytes = ypBytes + y2Bytes;

    const size_t sz_part = (size_t)NSEG_H * HW * 4;        // 1.28 MB
    const size_t sz_degb = (size_t)HW * 4;                 // 80 KB
    const size_t sz_buck = (size_t)NCHUNK * NW * RCAP * 4; // 6.23 MB
    const size_t sz_hdr  = (size_t)NCHUNK * NW * 4;        // 41 KB
    const size_t per_t = sz_part + sz_degb + sz_buck + sz_hdr;

    size_t avail = (ws_size > headBytes) ? ws_size - headBytes : 0;
    int Tg = (int)(avail / per_t);
    if (Tg > TT) Tg = TT;
    if (Tg < 1) Tg = 1;

    size_t ofs = headBytes;
    unsigned int* part = (unsigned int*)(ws + ofs); ofs += (size_t)Tg * sz_part;
    unsigned int* degb = (unsigned int*)(ws + ofs); ofs += (size_t)Tg * sz_degb;
    unsigned int* hdr  = (unsigned int*)(ws + ofs); ofs += (size_t)Tg * sz_hdr;
    unsigned int* buck = (unsigned int*)(ws + ofs);

    for (int t0 = 0; t0 < TT; t0 += Tg) {
        int tc = (TT - t0 < Tg) ? (TT - t0) : Tg;

        dim3 gh(NSEG_H, tc);
        k_hist<<<gh, 256, 0, stream>>>(ei, part, t0);

        dim3 gm((HW + 255) / 256, tc);
        k_mdeg<<<gm, 256, 0, stream>>>(part, degb);

        dim3 gp(NSEG_B, tc);
        k_part<<<gp, 256, 0, stream>>>(ei, buck, hdr, t0);

        dim3 gs(NCHUNK, tc);
        k_scat<<<gs, 512, 0, stream>>>(g, degb, buck, hdr, yp, t0);
    }

    k_fold<<<TT, 512, 0, stream>>>(yp, y2);
    k_lstm<<<BB, 256, 0, stream>>>(y2, Wg, bg, Wih, Whh, bih, bhh, Wfc, bfc, out);
}